// Round 1
// baseline (89.941 us; speedup 1.0000x reference)
//
#include <hip/hip_runtime.h>
#include <hip/hip_bf16.h>

#define NB 8192
#define DD 256
#define INV_T (1.0f/0.07f)
#define NSPLIT 8
#define BM 128
#define BN 64
#define COLS_PER_SPLIT (NB/NSPLIT)   // 1024
#define NITER (COLS_PER_SPLIT/BN)    // 16

typedef __attribute__((ext_vector_type(8))) short s8v;   // 8 bf16
typedef __attribute__((ext_vector_type(4))) float f4v;   // 4 f32 acc

// workspace layout (bytes)
#define OFF_FB   0                        // bf16 normalized features: 8192*256*2 = 4 MB
#define OFF_HIST 4194304                  // int[128]
#define OFF_SE   4195328                  // f32 [NSPLIT][NB]
#define OFF_SP   (OFF_SE + 262144)
#define OFF_SA   (OFF_SP + 262144)
#define OFF_CL   (OFF_SA + 262144)        // f32[32] chunk loss
#define OFF_CV   (OFF_CL + 128)           // f32[32] chunk valid count

__global__ void k_zero(int* __restrict__ hist) {
    hist[threadIdx.x] = 0;
}

// one block per row: normalize, cast to bf16, histogram labels
__global__ void k_norm(const float* __restrict__ feat, const int* __restrict__ lab,
                       __hip_bfloat16* __restrict__ fb, int* __restrict__ hist) {
    const int row = blockIdx.x;
    const int t = threadIdx.x;
    float v = feat[row * DD + t];
    float s = v * v;
    #pragma unroll
    for (int d = 32; d; d >>= 1) s += __shfl_xor(s, d, 64);
    __shared__ float ps[4];
    if ((t & 63) == 0) ps[t >> 6] = s;
    __syncthreads();
    float tot = ps[0] + ps[1] + ps[2] + ps[3];
    float scale = 1.0f / fmaxf(sqrtf(tot), 1e-12f);
    fb[row * DD + t] = __float2bfloat16(v * scale);
    if (t == 0) atomicAdd(&hist[lab[row]], 1);
}

// main fused sim + row-reduction kernel
// grid (NB/BM, NSPLIT), block 256 (4 waves); wave owns 32 rows, A in regs, B staged in LDS
__launch_bounds__(256)
__global__ void k_main(const __hip_bfloat16* __restrict__ fb,
                       const int* __restrict__ lab,
                       float* __restrict__ SE, float* __restrict__ SP, float* __restrict__ SA) {
    __shared__ __align__(16) char ldsB[BN * DD * 2];  // 32 KB
    const int tid = threadIdx.x;
    const int w = tid >> 6;
    const int l = tid & 63;
    const int l15 = l & 15, lg = l >> 4;
    const int rb = blockIdx.x, sp = blockIdx.y;
    const int wbase = rb * BM + w * 32;

    // A fragments: rows wbase + m*16 + l15, k = kk*32 + lg*8 + [0..7]
    s8v a[2][8];
    #pragma unroll
    for (int m = 0; m < 2; m++)
        #pragma unroll
        for (int kk = 0; kk < 8; kk++)
            a[m][kk] = *(const s8v*)(fb + (wbase + m * 16 + l15) * DD + kk * 32 + lg * 8);

    // labels of the 8 rows this lane accumulates (rows wbase + m*16 + lg*4 + r)
    int labr[8];
    #pragma unroll
    for (int m = 0; m < 2; m++)
        #pragma unroll
        for (int r = 0; r < 4; r++)
            labr[m * 4 + r] = lab[wbase + m * 16 + lg * 4 + r];

    float sE[8], sPp[8], sAa[8];
    #pragma unroll
    for (int i = 0; i < 8; i++) { sE[i] = 0.f; sPp[i] = 0.f; sAa[i] = 0.f; }

    const int col0 = sp * COLS_PER_SPLIT;
    for (int it = 0; it < NITER; it++) {
        const int cb = col0 + it * BN;
        __syncthreads();   // previous iter's LDS reads done
        // stage B tile (BN x DD bf16), swizzled: byte ^= (row&7)<<4
        #pragma unroll
        for (int i = 0; i < 8; i++) {
            int c  = tid + i * 256;
            int br = c >> 5, ck = c & 31;
            s8v v = *(const s8v*)(fb + (cb + br) * DD + ck * 8);
            int addr = (br * 512 + ck * 16) ^ ((br & 7) << 4);
            *(s8v*)(ldsB + addr) = v;
        }
        __syncthreads();

        f4v acc[2][4];
        #pragma unroll
        for (int m = 0; m < 2; m++)
            #pragma unroll
            for (int n = 0; n < 4; n++)
                acc[m][n] = (f4v){0.f, 0.f, 0.f, 0.f};

        #pragma unroll
        for (int kk = 0; kk < 8; kk++) {
            s8v bfr[4];
            #pragma unroll
            for (int n = 0; n < 4; n++) {
                int br = n * 16 + l15;
                int addr = (br * 512 + kk * 64 + lg * 16) ^ ((br & 7) << 4);
                bfr[n] = *(const s8v*)(ldsB + addr);
            }
            #pragma unroll
            for (int m = 0; m < 2; m++)
                #pragma unroll
                for (int n = 0; n < 4; n++)
                    acc[m][n] = __builtin_amdgcn_mfma_f32_16x16x32_bf16(a[m][kk], bfr[n], acc[m][n], 0, 0, 0);
        }

        // epilogue: logit = (dot-1)/temp (max-subtract of self-sim folded in analytically)
        #pragma unroll
        for (int n = 0; n < 4; n++) {
            int col = cb + n * 16 + l15;
            int lc = lab[col];
            #pragma unroll
            for (int m = 0; m < 2; m++)
                #pragma unroll
                for (int r = 0; r < 4; r++) {
                    int row = wbase + m * 16 + lg * 4 + r;
                    int idx = m * 4 + r;
                    float logit = (acc[m][n][r] - 1.0f) * INV_T;
                    float e = fmaxf(__expf(logit), 1e-8f);
                    bool self = (row == col);
                    if (!self) {
                        sE[idx] += e;
                        sAa[idx] += logit;
                        if (lc == labr[idx]) sPp[idx] += logit;
                    }
                }
        }
    }

    // reduce across the 16 lanes (l15) of each group
    #pragma unroll
    for (int idx = 0; idx < 8; idx++) {
        #pragma unroll
        for (int d = 1; d < 16; d <<= 1) {
            sE[idx]  += __shfl_xor(sE[idx], d, 16);
            sPp[idx] += __shfl_xor(sPp[idx], d, 16);
            sAa[idx] += __shfl_xor(sAa[idx], d, 16);
        }
    }
    if (l15 == 0) {
        #pragma unroll
        for (int idx = 0; idx < 8; idx++) {
            int row = wbase + (idx >> 2) * 16 + lg * 4 + (idx & 3);
            SE[sp * NB + row] = sE[idx];
            SP[sp * NB + row] = sPp[idx];
            SA[sp * NB + row] = sAa[idx];
        }
    }
}

// per-row finalize; one block = one 256-row chunk (fallback is chunk-local)
__global__ void k_rows(const int* __restrict__ lab, const int* __restrict__ hist,
                       const float* __restrict__ SE, const float* __restrict__ SP,
                       const float* __restrict__ SA,
                       float* __restrict__ CL, float* __restrict__ CV) {
    const int t = threadIdx.x;
    const int row = blockIdx.x * 256 + t;
    float se = 0.f, sp_ = 0.f, sa = 0.f;
    #pragma unroll
    for (int s = 0; s < NSPLIT; s++) {
        se  += SE[s * NB + row];
        sp_ += SP[s * NB + row];
        sa  += SA[s * NB + row];
    }
    const int n = hist[lab[row]] - 1;
    __shared__ int flag;
    if (t == 0) flag = 0;
    __syncthreads();
    if (n > 0) atomicOr(&flag, 1);
    __syncthreads();
    const bool hp = (flag != 0);
    float lse = logf(se + 1e-8f);
    float pairs = hp ? (float)n : (float)(NB - 1);
    float psum  = hp ? sp_ : sa;
    bool valid = pairs > 0.f;
    float loss = valid ? (lse - psum / pairs) : 0.f;
    float vf = valid ? 1.f : 0.f;
    #pragma unroll
    for (int d = 32; d; d >>= 1) { loss += __shfl_xor(loss, d, 64); vf += __shfl_xor(vf, d, 64); }
    __shared__ float pl[4], pv[4];
    if ((t & 63) == 0) { pl[t >> 6] = loss; pv[t >> 6] = vf; }
    __syncthreads();
    if (t == 0) {
        CL[blockIdx.x] = pl[0] + pl[1] + pl[2] + pl[3];
        CV[blockIdx.x] = pv[0] + pv[1] + pv[2] + pv[3];
    }
}

__global__ void k_final(const float* __restrict__ CL, const float* __restrict__ CV,
                        float* __restrict__ out) {
    const int t = threadIdx.x;
    float lsum = (t < 32) ? CL[t] : 0.f;
    float vsum = (t < 32) ? CV[t] : 0.f;
    #pragma unroll
    for (int d = 32; d; d >>= 1) { lsum += __shfl_xor(lsum, d, 64); vsum += __shfl_xor(vsum, d, 64); }
    if (t == 0) {
        float mean = lsum / (vsum + 1e-8f);
        out[0] = mean;   // loss (reduction == 'mean')
        out[1] = vsum;   // total_pairs
        out[2] = mean;   // mean_loss
    }
}

extern "C" void kernel_launch(void* const* d_in, const int* in_sizes, int n_in,
                              void* d_out, int out_size, void* d_ws, size_t ws_size,
                              hipStream_t stream) {
    (void)in_sizes; (void)n_in; (void)out_size; (void)ws_size;
    const float* feat = (const float*)d_in[0];
    const int*   lab  = (const int*)d_in[1];
    char* ws = (char*)d_ws;
    __hip_bfloat16* fb = (__hip_bfloat16*)(ws + OFF_FB);
    int*   hist = (int*)(ws + OFF_HIST);
    float* SE = (float*)(ws + OFF_SE);
    float* SP = (float*)(ws + OFF_SP);
    float* SA = (float*)(ws + OFF_SA);
    float* CL = (float*)(ws + OFF_CL);
    float* CV = (float*)(ws + OFF_CV);
    float* out = (float*)d_out;

    hipLaunchKernelGGL(k_zero,  dim3(1), dim3(128), 0, stream, hist);
    hipLaunchKernelGGL(k_norm,  dim3(NB), dim3(256), 0, stream, feat, lab, fb, hist);
    hipLaunchKernelGGL(k_main,  dim3(NB / BM, NSPLIT), dim3(256), 0, stream, fb, lab, SE, SP, SA);
    hipLaunchKernelGGL(k_rows,  dim3(NB / 256), dim3(256), 0, stream, lab, hist, SE, SP, SA, CL, CV);
    hipLaunchKernelGGL(k_final, dim3(1), dim3(64), 0, stream, CL, CV, out);
}